// Round 2
// baseline (323.761 us; speedup 1.0000x reference)
//
#include <hip/hip_runtime.h>
#include <hip/hip_bf16.h>

// HMLSTMCell2: B=65536, H=128, gates = 513-wide GEMM (K=384) + pointwise epilogue.
// Gate columns 0..511 via bf16 MFMA 16x16x32; column 512 (sz -> hard threshold z_new)
// in fp64 fused into A staging. Weights pre-converted to bf16 (k-packed, column
// blocked) in d_ws.
// R4->R5: remove the W-LDS path entirely. Per-wave tile re-cut 32x128 -> 64x64
// (16 H-cols x 4 gates) so the 8 waves partition the 512 gemm-cols exactly and
// each wave loads its B-fragments straight from L2 into registers (4 coalesced
// dwordx4 per chunk, no redundancy). No global_load_lds, no hand vmcnt, no W
// double-buffer: the compiler emits counted vmcnt for the register W prefetch,
// which crosses the (lgkm-only) A-staging barrier freely. LDS 79.4->13.8 KB
// removes the 2-blocks/CU cliff. Epilogue cs/hs loads guarded (quad-uniform z
// branches). Numerics unchanged (same f2bf RNE, fp64 sz, epilogue math).

#define MT   64          // rows per block
#define BK   32          // K chunk
#define NKC  12          // 384 / 32
#define NT   512         // threads per block
#define COFF 8388608     // c_new offset in d_out (65536*128)
#define ZOFF 16777216    // z_new offset (2*65536*128)

using short8 = __attribute__((ext_vector_type(8))) short;  // 8 bf16 (4 VGPR)
using f32x4  = __attribute__((ext_vector_type(4))) float;  // MFMA acc frag

__device__ __forceinline__ unsigned short f2bf(float f) {
  union { float f; unsigned u; } v; v.f = f;
  unsigned r = (v.u + 0x7FFFu + ((v.u >> 16) & 1u)) >> 16;  // RNE truncate
  return (unsigned short)r;
}

__device__ __forceinline__ float sigm(float x)     { return 1.f / (1.f + __expf(-x)); }
__device__ __forceinline__ float tanh_fast(float x){ return 1.f - 2.f / (1.f + __expf(2.f * x)); }

// d_ws layout (identity units, no swizzle): element ((c*512 + n)*4 + u)*8 + j
// holds Wc[k = c*32 + u*8 + j][n], Wc = [W; R; U] (cols 0..511). Consumed by
// direct global->register fragment loads (lane (q,lr) of wave wv reads column
// n = g*128 + wv*16 + lr, unit u = q -> 16 cols x 64 B = 1 KB contiguous/instr).
__global__ void prep_weights(const float* __restrict__ W, const float* __restrict__ R,
                             const float* __restrict__ U, unsigned short* __restrict__ Wt) {
  int idx = blockIdx.x * blockDim.x + threadIdx.x;   // 0 .. 24575
  if (idx >= NKC * 512 * 4) return;
  int u  = idx & 3;            // 16B unit within column (k group)
  int n  = (idx >> 2) & 511;   // output column
  int c  = idx >> 11;          // K chunk
  int k0 = c * 32 + u * 8;     // global k of first element
  const float* src; int kb;
  if (k0 < 128)      { src = W; kb = 0;   }
  else if (k0 < 256) { src = R; kb = 128; }
  else               { src = U; kb = 256; }
  const float* colp = src + (size_t)(k0 - kb) * 513 + n;
  unsigned short vs[8];
  #pragma unroll
  for (int j = 0; j < 8; ++j) vs[j] = f2bf(colp[j * 513]);
  uint4 o;
  o.x = (unsigned)vs[0] | ((unsigned)vs[1] << 16);
  o.y = (unsigned)vs[2] | ((unsigned)vs[3] << 16);
  o.z = (unsigned)vs[4] | ((unsigned)vs[5] << 16);
  o.w = (unsigned)vs[6] | ((unsigned)vs[7] << 16);
  reinterpret_cast<uint4*>(Wt)[idx] = o;
}

__global__ __launch_bounds__(NT, 4)
void hmlstm_main(const float* __restrict__ hb, const float* __restrict__ hs,
                 const float* __restrict__ ht, const float* __restrict__ cs,
                 const float* __restrict__ zp, const float* __restrict__ zbp,
                 const float* __restrict__ W,  const float* __restrict__ R,
                 const float* __restrict__ U,  const float* __restrict__ b,
                 const unsigned short* __restrict__ Wt, float* __restrict__ out)
{
  __shared__ unsigned short ldsA[2][MT * BK];    // 8 KB, double-buffered A chunks
  __shared__ float  ldsWL[384];                  // fp32 col-512 weights (for sz)
  __shared__ double ldsSZ[NT];                   // sz partial reduce (fp64)
  // total 13824 B -> LDS no longer limits occupancy

  const int tid  = threadIdx.x;
  const int l    = tid & 63;
  const int wv   = tid >> 6;   // 0..7: 16-H-col slice owner
  const int q    = l >> 4;     // quad 0..3
  const int lr   = l & 15;
  const int row0 = blockIdx.x * MT;

  // stage fp32 column-512 weights (sz path)
  for (int k = tid; k < 384; k += NT) {
    ldsWL[k] = (k < 128) ? W[k * 513 + 512]
             : (k < 256) ? R[(k - 128) * 513 + 512]
                         : U[(k - 256) * 513 + 512];
  }

  // A-staging assignment: thread -> (row m, 4-float group p); fixed across chunks
  const int m    = tid >> 3;       // 0..63
  const int p    = tid & 7;        // 0..7
  const int arow = row0 + m;
  const float zbv = zbp[arow];
  const float zv  = zp[arow];
  double szacc = 0.0;

  f32x4 acc[4][4];                 // [row 16-group][gate], 64 AGPRs
  {
    f32x4 zf = {0.f, 0.f, 0.f, 0.f};
    #pragma unroll
    for (int i = 0; i < 4; ++i)
      #pragma unroll
      for (int j = 0; j < 4; ++j) acc[i][j] = zf;
  }

  // swizzled 8B half-slot for A staging (16B-unit XOR matches the read side;
  // spreads ds_read_b128 start banks to 2 lanes/bank = free per m136)
  const int aW = m * BK + (((p >> 1) ^ ((m >> 1) & 3)) * 8) + (p & 1) * 4;
  const size_t rowb = (size_t)arow * 128 + p * 4;

  auto loadA = [&](int c) -> f32x4 {
    const float* src = (c < 4) ? hb : (c < 8) ? hs : ht;
    return *(const f32x4*)(src + rowb + (c & 3) * 32);
  };
  auto consumeA = [&](int c, f32x4 v, int buf) {
    const float scale = (c < 4) ? zbv : (c < 8) ? 1.f : zv;
    v *= scale;
    const float* wl = ldsWL + c * 32 + p * 4;
    szacc += (double)v.x * wl[0] + (double)v.y * wl[1]
           + (double)v.z * wl[2] + (double)v.w * wl[3];
    uint2 pk;
    pk.x = (unsigned)f2bf(v.x) | ((unsigned)f2bf(v.y) << 16);
    pk.y = (unsigned)f2bf(v.z) | ((unsigned)f2bf(v.w) << 16);
    *(uint2*)&ldsA[buf][aW] = pk;
  };

  // per-lane W fragment base: column wv*16+lr, k-unit q
  const unsigned short* wp = Wt + (wv * 16 + lr) * 32 + q * 8;

  // ---- prologue ----
  f32x4 a0 = loadA(0);
  asm volatile("s_waitcnt lgkmcnt(0)" ::: "memory");
  __builtin_amdgcn_s_barrier();                    // ldsWL visible
  consumeA(0, a0, 0);                              // compiler waits vmcnt for a0
  f32x4 ain = loadA(1);
  short8 wf[4];
  #pragma unroll
  for (int g = 0; g < 4; ++g)
    wf[g] = *(const short8*)(wp + g * 4096);       // chunk 0 B-frags -> regs
  asm volatile("s_waitcnt lgkmcnt(0)" ::: "memory");
  __builtin_amdgcn_s_barrier();                    // ldsA[0] visible

  // ---- main loop: barrier drains lgkm only; W prefetch is register-tracked ----
  #pragma unroll
  for (int kc = 0; kc < NKC; ++kc) {
    const int cur = kc & 1;
    short8 af[4];
    #pragma unroll
    for (int s = 0; s < 4; ++s) {
      int mr = s * 16 + lr;                        // A[m = lane&15][k = q*8+j]
      af[s] = *(const short8*)&ldsA[cur][mr * BK + ((q ^ ((mr >> 1) & 3)) * 8)];
    }
    short8 wn[4];
    if (kc < NKC - 1) {
      #pragma unroll
      for (int g = 0; g < 4; ++g)                  // next chunk B-frags, in flight
        wn[g] = *(const short8*)(wp + (kc + 1) * 16384 + g * 4096);
      consumeA(kc + 1, ain, cur ^ 1);              // stage next A (scale/sz/pack)
      if (kc < NKC - 2) ain = loadA(kc + 2);
    }
    #pragma unroll
    for (int s = 0; s < 4; ++s)
      #pragma unroll
      for (int g = 0; g < 4; ++g)
        acc[s][g] = __builtin_amdgcn_mfma_f32_16x16x32_bf16(af[s], wf[g], acc[s][g], 0, 0, 0);
    if (kc < NKC - 1) {
      #pragma unroll
      for (int g = 0; g < 4; ++g) wf[g] = wn[g];
      asm volatile("s_waitcnt lgkmcnt(0)" ::: "memory");  // A writes+reads drained
      __builtin_amdgcn_s_barrier();
    }
  }

  // ---- z_new: fp64 sz reduce (8 partials per row), hard threshold sz > 0 ----
  ldsSZ[tid] = szacc;
  __syncthreads();
  if (tid < MT) {
    const double* pz = &ldsSZ[tid * 8];
    double ss = ((pz[0] + pz[1]) + (pz[2] + pz[3])) + ((pz[4] + pz[5]) + (pz[6] + pz[7]));
    float s = (float)ss + b[512];
    out[ZOFF + row0 + tid] = (s > 0.f) ? 1.f : 0.f;
  }

  // ---- epilogue: all four gates for (row,col) live in this lane's acc ----
  const int col = wv * 16 + lr;
  const float b0 = b[col], b1 = b[128 + col], b2 = b[256 + col], b3 = b[384 + col];
  #pragma unroll
  for (int s = 0; s < 4; ++s) {
    #pragma unroll
    for (int r = 0; r < 4; ++r) {
      const int row = row0 + s * 16 + q * 4 + r;   // C/D: row = quad*4 + reg
      const float zr  = zp[row];
      const float zbr = zbp[row];
      const size_t off = (size_t)row * 128 + col;  // C/D: col = lane&15 slice
      float si = acc[s][0][r] + b0;
      float sg = acc[s][1][r] + b1;
      float so = acc[s][2][r] + b2;
      float sf = acc[s][3][r] + b3;
      float iv = sigm(si);
      float gv = tanh_fast(sg);
      float ov = sigm(so);
      float fv = sigm(sf);
      float ig = iv * gv;
      float cv = 0.f, hv = 0.f;
      if (zr != 1.f) cv = cs[off];                 // quad-uniform guard
      const bool keep = (zr == 0.f) && (zbr == 0.f);
      if (keep) hv = hs[off];                      // quad-uniform guard
      float cn = (zr == 1.f) ? ig : ((zbr == 0.f) ? cv : cv * fv + ig);
      float hn = keep ? hv : tanh_fast(cn) * ov;
      out[off]        = hn;
      out[COFF + off] = cn;
    }
  }
}

extern "C" void kernel_launch(void* const* d_in, const int* in_sizes, int n_in,
                              void* d_out, int out_size, void* d_ws, size_t ws_size,
                              hipStream_t stream) {
  const float* hb  = (const float*)d_in[0];
  const float* hs  = (const float*)d_in[1];
  const float* ht  = (const float*)d_in[2];
  const float* cs  = (const float*)d_in[3];
  const float* zp  = (const float*)d_in[4];
  const float* zbp = (const float*)d_in[5];
  const float* W   = (const float*)d_in[6];
  const float* R   = (const float*)d_in[7];
  const float* U   = (const float*)d_in[8];
  const float* b   = (const float*)d_in[9];
  unsigned short* Wt = (unsigned short*)d_ws;   // 12*512*32*2 = 393216 B
  float* out = (float*)d_out;

  prep_weights<<<dim3(96), dim3(256), 0, stream>>>(W, R, U, Wt);
  hmlstm_main<<<dim3(65536 / MT), dim3(NT), 0, stream>>>(
      hb, hs, ht, cs, zp, zbp, W, R, U, b, Wt, out);
}

// Round 3
// 249.895 us; speedup vs baseline: 1.2956x; 1.2956x over previous
//
#include <hip/hip_runtime.h>
#include <hip/hip_bf16.h>

// HMLSTMCell2: B=65536, H=128, gates = 513-wide GEMM (K=384) + pointwise epilogue.
// Gate columns 0..511 via bf16 MFMA 16x16x32; column 512 (sz -> hard threshold z_new)
// in fp64 fused into A staging. Weights pre-converted to bf16 in d_ws, laid out so
// each wave's 8 B-fragments per chunk are contiguous (frag stride 1024 B).
// R5->R6: R5's 16-col-per-wave output slices split every 128 B output line across
// two waves -> partial-line RMW at L2/HBM -> WRITE_SIZE 66->309 MB (+100 us).
// Restore R4's tile cut (wave = 32 rows x {4 gates x 32 H-cols}; acc[2][8]=64 AGPR):
// each 128 B line of out is written whole by one wave (66 MB writes), while KEEPING
// R5's reg-direct W loads (no W-LDS, no hand vmcnt, 13.8 KB LDS, 4 waves/SIMD).
// Wave pairs duplicate W reads (786 MB, L2/L1-resident Wt = 384 KB -> cheap).

#define MT   64          // rows per block
#define BK   32          // K chunk
#define NKC  12          // 384 / 32
#define NT   512         // threads per block
#define COFF 8388608     // c_new offset in d_out (65536*128)
#define ZOFF 16777216    // z_new offset (2*65536*128)

using short8 = __attribute__((ext_vector_type(8))) short;  // 8 bf16 (4 VGPR)
using f32x4  = __attribute__((ext_vector_type(4))) float;  // MFMA acc frag

__device__ __forceinline__ unsigned short f2bf(float f) {
  union { float f; unsigned u; } v; v.f = f;
  unsigned r = (v.u + 0x7FFFu + ((v.u >> 16) & 1u)) >> 16;  // RNE truncate
  return (unsigned short)r;
}

__device__ __forceinline__ float sigm(float x)     { return 1.f / (1.f + __expf(-x)); }
__device__ __forceinline__ float tanh_fast(float x){ return 1.f - 2.f / (1.f + __expf(2.f * x)); }

// d_ws layout (wave-fragment blocked): short index
//   ((((c*4 + s)*8 + tn)*16 + x)*4 + u)*8 + j
// holds Wc[k = c*32 + u*8 + j][n],  n = (tn>>1)*128 + s*32 + (tn&1)*16 + x,
// Wc = [W; R; U] (cols 0..511). A wave with col-slice s reads frag tn of chunk c
// at byte (c*32768 + s*8192 + tn*1024 + lr*64 + q*16): one moving per-lane offset,
// frag stride 1024 B (imm-foldable), 1 KB contiguous per load instr (coalesced).
__global__ void prep_weights(const float* __restrict__ W, const float* __restrict__ R,
                             const float* __restrict__ U, unsigned short* __restrict__ Wt) {
  int idx = blockIdx.x * blockDim.x + threadIdx.x;   // 0 .. 24575, one 16B unit each
  if (idx >= NKC * 512 * 4) return;
  int u  = idx & 3;            // k unit within chunk
  int x  = (idx >> 2) & 15;    // col within 16-slice
  int tn = (idx >> 6) & 7;     // frag: gate = tn>>1, half = tn&1
  int s  = (idx >> 9) & 3;     // wave col-slice
  int c  = idx >> 11;          // K chunk
  int n  = (tn >> 1) * 128 + s * 32 + (tn & 1) * 16 + x;  // gemm column
  int k0 = c * 32 + u * 8;     // global k of first element
  const float* src; int kb;
  if (k0 < 128)      { src = W; kb = 0;   }
  else if (k0 < 256) { src = R; kb = 128; }
  else               { src = U; kb = 256; }
  const float* colp = src + (size_t)(k0 - kb) * 513 + n;
  unsigned short vs[8];
  #pragma unroll
  for (int j = 0; j < 8; ++j) vs[j] = f2bf(colp[j * 513]);
  uint4 o;
  o.x = (unsigned)vs[0] | ((unsigned)vs[1] << 16);
  o.y = (unsigned)vs[2] | ((unsigned)vs[3] << 16);
  o.z = (unsigned)vs[4] | ((unsigned)vs[5] << 16);
  o.w = (unsigned)vs[6] | ((unsigned)vs[7] << 16);
  reinterpret_cast<uint4*>(Wt)[idx] = o;
}

__global__ __launch_bounds__(NT, 4)
void hmlstm_main(const float* __restrict__ hb, const float* __restrict__ hs,
                 const float* __restrict__ ht, const float* __restrict__ cs,
                 const float* __restrict__ zp, const float* __restrict__ zbp,
                 const float* __restrict__ W,  const float* __restrict__ R,
                 const float* __restrict__ U,  const float* __restrict__ b,
                 const unsigned short* __restrict__ Wt, float* __restrict__ out)
{
  __shared__ unsigned short ldsA[2][MT * BK];    // 8 KB, double-buffered A chunks
  __shared__ float  ldsWL[384];                  // fp32 col-512 weights (for sz)
  __shared__ double ldsSZ[NT];                   // sz partial reduce (fp64)
  // total 13824 B -> occupancy limited by regs (128/wave -> 4 waves/SIMD)

  const int tid  = threadIdx.x;
  const int l    = tid & 63;
  const int wv   = tid >> 6;   // 0..7
  const int ws   = wv & 3;     // 32-H-col slice
  const int wr   = wv >> 2;    // row half (32 rows)
  const int q    = l >> 4;     // quad 0..3
  const int lr   = l & 15;
  const int row0 = blockIdx.x * MT;

  // stage fp32 column-512 weights (sz path)
  for (int k = tid; k < 384; k += NT) {
    ldsWL[k] = (k < 128) ? W[k * 513 + 512]
             : (k < 256) ? R[(k - 128) * 513 + 512]
                         : U[(k - 256) * 513 + 512];
  }

  // A-staging assignment: thread -> (row m, 4-float group p); fixed across chunks
  const int m    = tid >> 3;       // 0..63
  const int p    = tid & 7;        // 0..7
  const int arow = row0 + m;
  const float zbv = zbp[arow];
  const float zv  = zp[arow];
  double szacc = 0.0;

  f32x4 acc[2][8];                 // [row 16-group][gate*2+half], 64 AGPRs
  {
    f32x4 zf = {0.f, 0.f, 0.f, 0.f};
    #pragma unroll
    for (int i = 0; i < 2; ++i)
      #pragma unroll
      for (int j = 0; j < 8; ++j) acc[i][j] = zf;
  }

  // swizzled 8B half-slot for A staging (16B-unit XOR matches the read side;
  // spreads ds_read_b128 start banks to 2 lanes/bank = free per m136)
  const int aW = m * BK + (((p >> 1) ^ ((m >> 1) & 3)) * 8) + (p & 1) * 4;
  const size_t rowb = (size_t)arow * 128 + p * 4;

  auto loadA = [&](int c) -> f32x4 {
    const float* src = (c < 4) ? hb : (c < 8) ? hs : ht;
    return *(const f32x4*)(src + rowb + (c & 3) * 32);
  };
  auto consumeA = [&](int c, f32x4 v, int buf) {
    const float scale = (c < 4) ? zbv : (c < 8) ? 1.f : zv;
    v *= scale;
    const float* wl = ldsWL + c * 32 + p * 4;
    szacc += (double)v.x * wl[0] + (double)v.y * wl[1]
           + (double)v.z * wl[2] + (double)v.w * wl[3];
    uint2 pk;
    pk.x = (unsigned)f2bf(v.x) | ((unsigned)f2bf(v.y) << 16);
    pk.y = (unsigned)f2bf(v.z) | ((unsigned)f2bf(v.w) << 16);
    *(uint2*)&ldsA[buf][aW] = pk;
  };

  // per-lane W fragment pointer: chunk stride 16384 shorts (32 KB), frag stride
  // 512 shorts (1024 B, imm-foldable); covers cols (tn>>1)*128 + ws*32 + (tn&1)*16 + lr
  const unsigned short* wkc = Wt + (size_t)ws * 4096 + lr * 32 + q * 8;

  // ---- prologue ----
  f32x4 a0 = loadA(0);
  short8 wf[8];
  #pragma unroll
  for (int tn = 0; tn < 8; ++tn)
    wf[tn] = *(const short8*)(wkc + tn * 512);     // chunk 0 B-frags in flight
  asm volatile("s_waitcnt lgkmcnt(0)" ::: "memory");
  __builtin_amdgcn_s_barrier();                    // ldsWL visible
  consumeA(0, a0, 0);                              // waits vmcnt for a0 only
  f32x4 ain = loadA(1);
  asm volatile("s_waitcnt lgkmcnt(0)" ::: "memory");
  __builtin_amdgcn_s_barrier();                    // ldsA[0] visible

  // ---- main loop: one lgkm-only barrier per chunk; W rides register prefetch ----
  #pragma unroll 1
  for (int kc = 0; kc < NKC; ++kc) {
    const int cur = kc & 1;
    short8 af[2];
    #pragma unroll
    for (int s = 0; s < 2; ++s) {
      int mr = wr * 32 + s * 16 + lr;              // A[m = lane&15][k = q*8+j]
      af[s] = *(const short8*)&ldsA[cur][mr * BK + ((q ^ ((mr >> 1) & 3)) * 8)];
    }
    #pragma unroll
    for (int tn = 0; tn < 8; ++tn) {               // waits vmcnt for wf, ain stays
      acc[0][tn] = __builtin_amdgcn_mfma_f32_16x16x32_bf16(af[0], wf[tn], acc[0][tn], 0, 0, 0);
      acc[1][tn] = __builtin_amdgcn_mfma_f32_16x16x32_bf16(af[1], wf[tn], acc[1][tn], 0, 0, 0);
    }
    if (kc < NKC - 1) {
      #pragma unroll
      for (int tn = 0; tn < 8; ++tn)               // next chunk B-frags (WAR on wf
        wf[tn] = *(const short8*)(wkc + 16384 + tn * 512);  // after MFMA issue)
      consumeA(kc + 1, ain, cur ^ 1);              // stage next A (scale/sz/pack)
      if (kc < NKC - 2) ain = loadA(kc + 2);
      wkc += 16384;
      asm volatile("s_waitcnt lgkmcnt(0)" ::: "memory");  // A writes+reads drained
      __builtin_amdgcn_s_barrier();
    }
  }

  // ---- z_new: fp64 sz reduce (8 partials per row), hard threshold sz > 0 ----
  ldsSZ[tid] = szacc;
  __syncthreads();
  if (tid < MT) {
    const double* pz = &ldsSZ[tid * 8];
    double ss = ((pz[0] + pz[1]) + (pz[2] + pz[3])) + ((pz[4] + pz[5]) + (pz[6] + pz[7]));
    float s = (float)ss + b[512];
    out[ZOFF + row0 + tid] = (s > 0.f) ? 1.f : 0.f;
  }

  // ---- epilogue: wave owns 32 rows x 32 cols; each 128 B out-line written whole ----
  float bias[2][4];
  #pragma unroll
  for (int th = 0; th < 2; ++th) {
    const int col = ws * 32 + th * 16 + lr;
    bias[th][0] = b[col];       bias[th][1] = b[128 + col];
    bias[th][2] = b[256 + col]; bias[th][3] = b[384 + col];
  }
  #pragma unroll
  for (int s = 0; s < 2; ++s) {
    #pragma unroll
    for (int r = 0; r < 4; ++r) {
      const int row = row0 + wr * 32 + s * 16 + q * 4 + r;  // C/D: row = quad*4 + reg
      const float zr  = zp[row];
      const float zbr = zbp[row];
      const size_t rowoff = (size_t)row * 128;
      #pragma unroll
      for (int th = 0; th < 2; ++th) {
        const int col = ws * 32 + th * 16 + lr;             // C/D: col = lane&15
        const size_t off = rowoff + col;
        float si = acc[s][0 + th][r] + bias[th][0];
        float sg = acc[s][2 + th][r] + bias[th][1];
        float so = acc[s][4 + th][r] + bias[th][2];
        float sf = acc[s][6 + th][r] + bias[th][3];
        float iv = sigm(si);
        float gv = tanh_fast(sg);
        float ov = sigm(so);
        float fv = sigm(sf);
        float ig = iv * gv;
        float cv = 0.f, hv = 0.f;
        if (zr != 1.f) cv = cs[off];                 // row-uniform guard, whole lines
        const bool keep = (zr == 0.f) && (zbr == 0.f);
        if (keep) hv = hs[off];
        float cn = (zr == 1.f) ? ig : ((zbr == 0.f) ? cv : cv * fv + ig);
        float hn = keep ? hv : tanh_fast(cn) * ov;
        out[off]        = hn;
        out[COFF + off] = cn;
      }
    }
  }
}

extern "C" void kernel_launch(void* const* d_in, const int* in_sizes, int n_in,
                              void* d_out, int out_size, void* d_ws, size_t ws_size,
                              hipStream_t stream) {
  const float* hb  = (const float*)d_in[0];
  const float* hs  = (const float*)d_in[1];
  const float* ht  = (const float*)d_in[2];
  const float* cs  = (const float*)d_in[3];
  const float* zp  = (const float*)d_in[4];
  const float* zbp = (const float*)d_in[5];
  const float* W   = (const float*)d_in[6];
  const float* R   = (const float*)d_in[7];
  const float* U   = (const float*)d_in[8];
  const float* b   = (const float*)d_in[9];
  unsigned short* Wt = (unsigned short*)d_ws;   // 12*512*32*2 = 393216 B
  float* out = (float*)d_out;

  prep_weights<<<dim3(96), dim3(256), 0, stream>>>(W, R, U, Wt);
  hmlstm_main<<<dim3(65536 / MT), dim3(NT), 0, stream>>>(
      hb, hs, ht, cs, zp, zbp, W, R, U, b, Wt, out);
}